// Round 1
// baseline (1173.442 us; speedup 1.0000x reference)
//
#include <hip/hip_runtime.h>
#include <hip/hip_bf16.h>
#include <cstdint>
#include <cstddef>

typedef __bf16 bf16_t;
typedef __bf16 bf16x8 __attribute__((ext_vector_type(8)));
typedef __bf16 bf16x4 __attribute__((ext_vector_type(4)));
typedef float  f32x4  __attribute__((ext_vector_type(4)));

#define D_MODEL 1024
#define SEQ     2048
#define NHEADS  16
#define DHEAD   64
#define DFF     4096

// async global->LDS, 16B per lane; lds base must be wave-uniform (dest = base + lane*16)
__device__ __forceinline__ void async_ld16(void* lds, const void* g) {
    __builtin_amdgcn_global_load_lds(
        (__attribute__((address_space(1))) void*)(void*)(g),
        (__attribute__((address_space(3))) void*)(lds), 16, 0, 0);
}

// ---------------------------------------------------------------------------
// fp32 (K x N) -> bf16 transposed (N-rows x K), dst row stride = rs*K elems
// ---------------------------------------------------------------------------
__global__ __launch_bounds__(256)
void transpose_cast_kernel(const float* __restrict__ src, bf16_t* __restrict__ dst,
                           int K, int N, int rs)
{
    __shared__ float tile[32][33];
    const int bn = blockIdx.x * 32, bk = blockIdx.y * 32;
    const int tx = threadIdx.x & 31, ty = threadIdx.x >> 5;
#pragma unroll
    for (int i = 0; i < 32; i += 8)
        tile[ty + i][tx] = src[(size_t)(bk + ty + i) * N + bn + tx];
    __syncthreads();
#pragma unroll
    for (int i = 0; i < 32; i += 8) {
        const int n = bn + ty + i, kk = bk + tx;
        dst[(size_t)n * rs * K + kk] = (bf16_t)tile[tx][ty + i];
    }
}

// ---------------------------------------------------------------------------
// RMSNorm: fp32 row (1024) -> bf16 row
// ---------------------------------------------------------------------------
__global__ __launch_bounds__(256)
void rmsnorm_kernel(const float* __restrict__ x, const float* __restrict__ gw,
                    bf16_t* __restrict__ out)
{
    const int row = blockIdx.x, tid = threadIdx.x;
    const float4 v = ((const float4*)(x + (size_t)row * D_MODEL))[tid];
    float ss = v.x*v.x + v.y*v.y + v.z*v.z + v.w*v.w;
#pragma unroll
    for (int d = 1; d < 64; d <<= 1) ss += __shfl_xor(ss, d);
    __shared__ float red[4];
    if ((tid & 63) == 0) red[tid >> 6] = ss;
    __syncthreads();
    const float tot = red[0] + red[1] + red[2] + red[3];
    const float sc = rsqrtf(tot * (1.f / D_MODEL) + 1e-5f);
    const float4 gv = ((const float4*)gw)[tid];
    bf16x4 o;
    o[0] = (bf16_t)(v.x * sc * gv.x);
    o[1] = (bf16_t)(v.y * sc * gv.y);
    o[2] = (bf16_t)(v.z * sc * gv.z);
    o[3] = (bf16_t)(v.w * sc * gv.w);
    ((bf16x4*)(out + (size_t)row * D_MODEL))[tid] = o;
}

// ---------------------------------------------------------------------------
// GEMM: C[M,N] = A[M,K] (bf16 row-major) @ Bt[N,K]^T (bf16, N-major rows of K)
// 128x128 tile, BK=32, 256 thr = 4 waves (2x2 of 64x64), MFMA 16x16x32 bf16.
// LDS chunk layout: chunk (g,m) at index g*128+m (16B each) -> matches
// global_load_lds lane ordering, conflict-free frag reads.
// MODE 0: QKV + RoPE -> q/k/v [B,H,S,Dh] bf16
// MODE 1: y = res + C  (fp32 out)
// MODE 2: gate = silu(c_w1) * c_w3 (w1/w3 interleaved in Bt rows) -> bf16
// MODE 3: out = res + C (fp32, res may alias outf)
// ---------------------------------------------------------------------------
template <int MODE>
__global__ __launch_bounds__(256)
void gemm_kernel(const bf16_t* __restrict__ A, const bf16_t* __restrict__ Bt,
                 int M, int N, int K,
                 bf16_t* __restrict__ qo, bf16_t* __restrict__ ko, bf16_t* __restrict__ vo,
                 const float* res, float* outf, bf16_t* __restrict__ gate)
{
    __shared__ bf16x8 Al[512];
    __shared__ bf16x8 Bl[512];
    const int tid  = threadIdx.x;
    const int wave = tid >> 6;
    const int lane = tid & 63;
    const int r    = lane & 15;
    const int g    = lane >> 4;
    const int wm   = wave >> 1;
    const int wn   = wave & 1;
    const int row0 = blockIdx.y * 128;
    const int col0 = blockIdx.x * 128;

    const f32x4 fzero = {0.f, 0.f, 0.f, 0.f};
    f32x4 acc[4][4];
#pragma unroll
    for (int i = 0; i < 4; ++i)
#pragma unroll
        for (int j = 0; j < 4; ++j) acc[i][j] = fzero;

    const int p0 = tid, p1 = 256 + tid;
    const bf16_t* a0 = A  + (size_t)(row0 + (p0 & 127)) * K + (p0 >> 7) * 8;
    const bf16_t* a1 = A  + (size_t)(row0 + (p1 & 127)) * K + (p1 >> 7) * 8;
    const bf16_t* b0 = Bt + (size_t)(col0 + (p0 & 127)) * K + (p0 >> 7) * 8;
    const bf16_t* b1 = Bt + (size_t)(col0 + (p1 & 127)) * K + (p1 >> 7) * 8;
    bf16x8* la0 = &Al[wave * 64];
    bf16x8* la1 = &Al[256 + wave * 64];
    bf16x8* lb0 = &Bl[wave * 64];
    bf16x8* lb1 = &Bl[256 + wave * 64];

    for (int kt = 0; kt < K; kt += 32) {
        async_ld16(la0, a0 + kt);
        async_ld16(la1, a1 + kt);
        async_ld16(lb0, b0 + kt);
        async_ld16(lb1, b1 + kt);
        __syncthreads();
        bf16x8 af[4], bfr[4];
#pragma unroll
        for (int mt = 0; mt < 4; ++mt) af[mt]  = Al[g * 128 + wm * 64 + mt * 16 + r];
#pragma unroll
        for (int nt = 0; nt < 4; ++nt) bfr[nt] = Bl[g * 128 + wn * 64 + nt * 16 + r];
#pragma unroll
        for (int mt = 0; mt < 4; ++mt)
#pragma unroll
            for (int nt = 0; nt < 4; ++nt)
                acc[mt][nt] = __builtin_amdgcn_mfma_f32_16x16x32_bf16(
                    af[mt], bfr[nt], acc[mt][nt], 0, 0, 0);
        __syncthreads();
    }

    const int mbase = row0 + wm * 64 + g * 4;
    const int nbase = col0 + wn * 64 + r;
#pragma unroll
    for (int mt = 0; mt < 4; ++mt) {
#pragma unroll
        for (int nt = 0; nt < 4; ++nt) {
#pragma unroll
            for (int e = 0; e < 4; ++e) {
                float val = acc[mt][nt][e];
                const int grow = mbase + mt * 16 + e;
                const int gcol = nbase + nt * 16;
                if constexpr (MODE == 0) {
                    float partner = __shfl_xor(val, 1);
                    const int mat  = gcol >> 10;
                    const int d    = gcol & 1023;
                    const int head = d >> 6;
                    const int dh   = d & 63;
                    const int b    = grow >> 11;
                    const int s    = grow & 2047;
                    const size_t dst = ((size_t)(b * NHEADS + head) * SEQ + s) * DHEAD + dh;
                    if (mat == 2) {
                        vo[dst] = (bf16_t)val;
                    } else {
                        // inv_freq = 10000^(-(dh&~1)/64) ; ln(10000)/64 = 0.14391157
                        const float ang = (float)s * __expf((float)(dh & ~1) * -0.14391157f);
                        float sn, cs;
                        __sincosf(ang, &sn, &cs);
                        const float rv = (dh & 1) ? (partner * sn + val * cs)
                                                  : (val * cs - partner * sn);
                        (mat == 0 ? qo : ko)[dst] = (bf16_t)rv;
                    }
                } else if constexpr (MODE == 1 || MODE == 3) {
                    const size_t idx = (size_t)grow * D_MODEL + gcol;
                    outf[idx] = res[idx] + val;
                } else { // MODE 2: even combined col = w1, odd = w3
                    float partner = __shfl_xor(val, 1);
                    if (!(lane & 1)) {
                        const float sv = val / (1.f + __expf(-val));
                        gate[(size_t)grow * DFF + (gcol >> 1)] = (bf16_t)(sv * partner);
                    }
                }
            }
        }
    }
}

// ---------------------------------------------------------------------------
// Causal flash attention. q/k/v: [B,H,S,Dh] bf16 (q,k post-RoPE).
// Grid: (S/64, B*H). WG = 256 thr = 4 waves, each wave owns 16 query rows.
// K-blocks of 32 keys; QK^T and PV via mfma 16x16x32; online softmax.
// ---------------------------------------------------------------------------
__global__ __launch_bounds__(256)
void attn_kernel(const bf16_t* __restrict__ qb, const bf16_t* __restrict__ kvk,
                 const bf16_t* __restrict__ vb, bf16_t* __restrict__ ctx)
{
    __shared__ bf16_t Kl[32][80];     // [key][Dh], padded
    __shared__ bf16_t Vl[64][40];     // [Dh][key] (transposed), padded
    __shared__ bf16_t Pl[4][16][40];  // per-wave P round-trip [m][k], padded
    const int qblk = blockIdx.x;
    const int bh   = blockIdx.y;
    const int tid  = threadIdx.x;
    const int wave = tid >> 6;
    const int lane = tid & 63;
    const int r = lane & 15, g = lane >> 4;
    const size_t base = (size_t)bh * SEQ * DHEAD;
    const int q0 = qblk * 64 + wave * 16;

    bf16x8 qf[2];
#pragma unroll
    for (int kh = 0; kh < 2; ++kh)
        qf[kh] = *(const bf16x8*)(qb + base + (size_t)(q0 + r) * DHEAD + kh * 32 + g * 8);

    const f32x4 fzero = {0.f, 0.f, 0.f, 0.f};
    float mi[4], li[4];
    f32x4 O[4];
#pragma unroll
    for (int e = 0; e < 4; ++e) { mi[e] = -1e30f; li[e] = 0.f; }
#pragma unroll
    for (int nt = 0; nt < 4; ++nt) O[nt] = fzero;

    const int nkb = 2 * qblk + 2;
    const int srow = tid >> 3, schk = tid & 7;

    for (int kbi = 0; kbi < nkb; ++kbi) {
        { // stage K (row-major) and V (transposed) into LDS
            const size_t roff = base + (size_t)(kbi * 32 + srow) * DHEAD + schk * 8;
            *(bf16x8*)&Kl[srow][schk * 8] = *(const bf16x8*)(kvk + roff);
            bf16x8 vv = *(const bf16x8*)(vb + roff);
#pragma unroll
            for (int j = 0; j < 8; ++j) Vl[schk * 8 + j][srow] = vv[j];
        }
        __syncthreads();
        const bool active = (kbi * 32) <= (q0 + 15);
        if (active) {
            f32x4 s0 = fzero, s1 = fzero;
            {
                bf16x8 k00 = *(const bf16x8*)&Kl[r][g * 8];
                bf16x8 k01 = *(const bf16x8*)&Kl[r][32 + g * 8];
                bf16x8 k10 = *(const bf16x8*)&Kl[16 + r][g * 8];
                bf16x8 k11 = *(const bf16x8*)&Kl[16 + r][32 + g * 8];
                s0 = __builtin_amdgcn_mfma_f32_16x16x32_bf16(qf[0], k00, s0, 0, 0, 0);
                s0 = __builtin_amdgcn_mfma_f32_16x16x32_bf16(qf[1], k01, s0, 0, 0, 0);
                s1 = __builtin_amdgcn_mfma_f32_16x16x32_bf16(qf[0], k10, s1, 0, 0, 0);
                s1 = __builtin_amdgcn_mfma_f32_16x16x32_bf16(qf[1], k11, s1, 0, 0, 0);
            }
            float sc0[4], sc1[4];
#pragma unroll
            for (int e = 0; e < 4; ++e) {
                const int qi = q0 + g * 4 + e;
                const int kj = kbi * 32 + r;
                sc0[e] = (kj <= qi)      ? s0[e] * 0.125f : -1e30f;
                sc1[e] = (kj + 16 <= qi) ? s1[e] * 0.125f : -1e30f;
            }
#pragma unroll
            for (int e = 0; e < 4; ++e) {
                float mx = fmaxf(sc0[e], sc1[e]);
#pragma unroll
                for (int d = 1; d < 16; d <<= 1) mx = fmaxf(mx, __shfl_xor(mx, d));
                const float mnew = fmaxf(mi[e], mx);
                const float p0v = __expf(sc0[e] - mnew);
                const float p1v = __expf(sc1[e] - mnew);
                float rs = p0v + p1v;
#pragma unroll
                for (int d = 1; d < 16; d <<= 1) rs += __shfl_xor(rs, d);
                const float alpha = __expf(mi[e] - mnew);
                li[e] = li[e] * alpha + rs;
                mi[e] = mnew;
#pragma unroll
                for (int nt = 0; nt < 4; ++nt) O[nt][e] *= alpha;
                Pl[wave][g * 4 + e][r]      = (bf16_t)p0v;
                Pl[wave][g * 4 + e][16 + r] = (bf16_t)p1v;
            }
            bf16x8 pf = *(const bf16x8*)&Pl[wave][r][g * 8];
#pragma unroll
            for (int nt = 0; nt < 4; ++nt) {
                bf16x8 vf = *(const bf16x8*)&Vl[nt * 16 + r][g * 8];
                O[nt] = __builtin_amdgcn_mfma_f32_16x16x32_bf16(pf, vf, O[nt], 0, 0, 0);
            }
        }
        __syncthreads();
    }
    const int b = bh >> 4, head = bh & 15;
#pragma unroll
    for (int e = 0; e < 4; ++e) {
        const float inv = 1.f / li[e];
        const int qi = q0 + g * 4 + e;
        const size_t rowo = (size_t)(b * SEQ + qi) * D_MODEL + head * DHEAD + r;
#pragma unroll
        for (int nt = 0; nt < 4; ++nt)
            ctx[rowo + nt * 16] = (bf16_t)(O[nt][e] * inv);
    }
}

// ---------------------------------------------------------------------------
extern "C" void kernel_launch(void* const* d_in, const int* in_sizes, int n_in,
                              void* d_out, int out_size, void* d_ws, size_t ws_size,
                              hipStream_t stream)
{
    (void)in_sizes; (void)n_in; (void)out_size; (void)ws_size;
    const float* x  = (const float*)d_in[0];
    const float* g1 = (const float*)d_in[2];
    const float* g2 = (const float*)d_in[3];
    const float* wq = (const float*)d_in[4];
    const float* wk = (const float*)d_in[5];
    const float* wv = (const float*)d_in[6];
    const float* wo = (const float*)d_in[7];
    const float* w1 = (const float*)d_in[8];
    const float* w2 = (const float*)d_in[9];
    const float* w3 = (const float*)d_in[10];
    float* out = (float*)d_out;
    char* ws = (char*)d_ws;
    const size_t MB = 1ull << 20;
    // ws layout (112 MB): weights bf16^T | h | q | k | v | ctx (gate overlays q..ctx)
    bf16_t* wqkvT = (bf16_t*)(ws + 0);        // 3072 x 1024
    bf16_t* woT   = (bf16_t*)(ws + 6  * MB);  // 1024 x 1024
    bf16_t* w13T  = (bf16_t*)(ws + 8  * MB);  // 8192 x 1024 (w1/w3 interleaved)
    bf16_t* w2T   = (bf16_t*)(ws + 24 * MB);  // 1024 x 4096
    bf16_t* hbuf  = (bf16_t*)(ws + 32 * MB);  // 8192 x 1024 (h, then h2)
    bf16_t* qbuf  = (bf16_t*)(ws + 48 * MB);
    bf16_t* kbuf  = (bf16_t*)(ws + 64 * MB);
    bf16_t* vbuf  = (bf16_t*)(ws + 80 * MB);
    bf16_t* ctx   = (bf16_t*)(ws + 96 * MB);
    bf16_t* gate  = (bf16_t*)(ws + 48 * MB);  // 8192 x 4096, reuses q/k/v/ctx

    dim3 blk(256);
    transpose_cast_kernel<<<dim3(32, 32),  blk, 0, stream>>>(wq, wqkvT,             1024, 1024, 1);
    transpose_cast_kernel<<<dim3(32, 32),  blk, 0, stream>>>(wk, wqkvT + 1024*1024, 1024, 1024, 1);
    transpose_cast_kernel<<<dim3(32, 32),  blk, 0, stream>>>(wv, wqkvT + 2048*1024, 1024, 1024, 1);
    transpose_cast_kernel<<<dim3(32, 32),  blk, 0, stream>>>(wo, woT,               1024, 1024, 1);
    transpose_cast_kernel<<<dim3(128, 32), blk, 0, stream>>>(w1, w13T,              1024, 4096, 2);
    transpose_cast_kernel<<<dim3(128, 32), blk, 0, stream>>>(w3, w13T + 1024,       1024, 4096, 2);
    transpose_cast_kernel<<<dim3(32, 128), blk, 0, stream>>>(w2, w2T,               4096, 1024, 1);

    rmsnorm_kernel<<<dim3(8192), blk, 0, stream>>>(x, g1, hbuf);

    gemm_kernel<0><<<dim3(24, 64), blk, 0, stream>>>(hbuf, wqkvT, 8192, 3072, 1024,
        qbuf, kbuf, vbuf, nullptr, nullptr, nullptr);

    attn_kernel<<<dim3(32, 64), blk, 0, stream>>>(qbuf, kbuf, vbuf, ctx);

    gemm_kernel<1><<<dim3(8, 64), blk, 0, stream>>>(ctx, woT, 8192, 1024, 1024,
        nullptr, nullptr, nullptr, x, out, nullptr);

    rmsnorm_kernel<<<dim3(8192), blk, 0, stream>>>(out, g2, hbuf);

    gemm_kernel<2><<<dim3(64, 64), blk, 0, stream>>>(hbuf, w13T, 8192, 8192, 1024,
        nullptr, nullptr, nullptr, nullptr, nullptr, gate);

    gemm_kernel<3><<<dim3(8, 64), blk, 0, stream>>>(gate, w2T, 8192, 1024, 4096,
        nullptr, nullptr, nullptr, out, out, nullptr);
}

// Round 2
// 946.565 us; speedup vs baseline: 1.2397x; 1.2397x over previous
//
#include <hip/hip_runtime.h>
#include <hip/hip_bf16.h>
#include <cstdint>
#include <cstddef>

typedef __bf16 bf16_t;
typedef __bf16 bf16x8 __attribute__((ext_vector_type(8)));
typedef __bf16 bf16x4 __attribute__((ext_vector_type(4)));
typedef float  f32x4  __attribute__((ext_vector_type(4)));

#define D_MODEL 1024
#define SEQ     2048
#define NHEADS  16
#define DHEAD   64
#define DFF     4096

// async global->LDS, 16B per lane; lds base must be wave-uniform (dest = base + lane*16)
__device__ __forceinline__ void async_ld16(void* lds, const void* g) {
    __builtin_amdgcn_global_load_lds(
        (__attribute__((address_space(1))) void*)(void*)(g),
        (__attribute__((address_space(3))) void*)(lds), 16, 0, 0);
}

// ---------------------------------------------------------------------------
// fp32 (K x N) -> bf16 transposed (N-rows x K), dst row stride = rs*K elems
// ---------------------------------------------------------------------------
__global__ __launch_bounds__(256)
void transpose_cast_kernel(const float* __restrict__ src, bf16_t* __restrict__ dst,
                           int K, int N, int rs)
{
    __shared__ float tile[32][33];
    const int bn = blockIdx.x * 32, bk = blockIdx.y * 32;
    const int tx = threadIdx.x & 31, ty = threadIdx.x >> 5;
#pragma unroll
    for (int i = 0; i < 32; i += 8)
        tile[ty + i][tx] = src[(size_t)(bk + ty + i) * N + bn + tx];
    __syncthreads();
#pragma unroll
    for (int i = 0; i < 32; i += 8) {
        const int n = bn + ty + i, kk = bk + tx;
        dst[(size_t)n * rs * K + kk] = (bf16_t)tile[tx][ty + i];
    }
}

// ---------------------------------------------------------------------------
// bf16 V [bh][s][dh] -> vT [bh][dh][s], 64x64 tiles, conflict-aware LDS
// ---------------------------------------------------------------------------
__global__ __launch_bounds__(256)
void transpose_v_kernel(const bf16_t* __restrict__ v, bf16_t* __restrict__ vt)
{
    __shared__ bf16_t T[64 * 66];   // [dh][s], stride 66
    const int bh = blockIdx.y, s0 = blockIdx.x * 64;
    const int tid = threadIdx.x;
    const size_t vb = (size_t)bh * SEQ * DHEAD;
#pragma unroll
    for (int h = 0; h < 2; ++h) {
        const int s = h * 32 + (tid >> 3), dc = (tid & 7) * 8;
        const bf16x8 vv = *(const bf16x8*)(v + vb + (size_t)(s0 + s) * DHEAD + dc);
#pragma unroll
        for (int j = 0; j < 8; ++j) T[(dc + j) * 66 + s] = vv[j];
    }
    __syncthreads();
    const size_t tb = (size_t)bh * DHEAD * SEQ;
    const uint32_t* Tw = (const uint32_t*)T;
#pragma unroll
    for (int h = 0; h < 2; ++h) {
        const int dh = h * 32 + (tid >> 3), kc = (tid & 7) * 8;
        uint4 o;
        o.x = Tw[dh * 33 + kc / 2 + 0];
        o.y = Tw[dh * 33 + kc / 2 + 1];
        o.z = Tw[dh * 33 + kc / 2 + 2];
        o.w = Tw[dh * 33 + kc / 2 + 3];
        *(uint4*)(vt + tb + (size_t)dh * SEQ + s0 + kc) = o;
    }
}

// ---------------------------------------------------------------------------
// RMSNorm: fp32 row (1024) -> bf16 row
// ---------------------------------------------------------------------------
__global__ __launch_bounds__(256)
void rmsnorm_kernel(const float* __restrict__ x, const float* __restrict__ gw,
                    bf16_t* __restrict__ out)
{
    const int row = blockIdx.x, tid = threadIdx.x;
    const float4 v = ((const float4*)(x + (size_t)row * D_MODEL))[tid];
    float ss = v.x*v.x + v.y*v.y + v.z*v.z + v.w*v.w;
#pragma unroll
    for (int d = 1; d < 64; d <<= 1) ss += __shfl_xor(ss, d);
    __shared__ float red[4];
    if ((tid & 63) == 0) red[tid >> 6] = ss;
    __syncthreads();
    const float tot = red[0] + red[1] + red[2] + red[3];
    const float sc = rsqrtf(tot * (1.f / D_MODEL) + 1e-5f);
    const float4 gv = ((const float4*)gw)[tid];
    bf16x4 o;
    o[0] = (bf16_t)(v.x * sc * gv.x);
    o[1] = (bf16_t)(v.y * sc * gv.y);
    o[2] = (bf16_t)(v.z * sc * gv.z);
    o[3] = (bf16_t)(v.w * sc * gv.w);
    ((bf16x4*)(out + (size_t)row * D_MODEL))[tid] = o;
}

// ---------------------------------------------------------------------------
// GEMM: C[M,N] = A[M,K] (bf16 row-major) @ Bt[N,K]^T
// MODE 0: QKV + RoPE -> q(*0.125)/k/v [B,H,S,Dh] bf16
// MODE 1: y = res + C  (fp32 out)
// MODE 2: gate = silu(c_w1) * c_w3 -> bf16
// MODE 3: out = res + C (fp32, res may alias outf)
// ---------------------------------------------------------------------------
template <int MODE>
__global__ __launch_bounds__(256)
void gemm_kernel(const bf16_t* __restrict__ A, const bf16_t* __restrict__ Bt,
                 int M, int N, int K,
                 bf16_t* __restrict__ qo, bf16_t* __restrict__ ko, bf16_t* __restrict__ vo,
                 const float* res, float* outf, bf16_t* __restrict__ gate)
{
    __shared__ bf16x8 Al[512];
    __shared__ bf16x8 Bl[512];
    const int tid  = threadIdx.x;
    const int wave = tid >> 6;
    const int lane = tid & 63;
    const int r    = lane & 15;
    const int g    = lane >> 4;
    const int wm   = wave >> 1;
    const int wn   = wave & 1;
    const int row0 = blockIdx.y * 128;
    const int col0 = blockIdx.x * 128;

    const f32x4 fzero = {0.f, 0.f, 0.f, 0.f};
    f32x4 acc[4][4];
#pragma unroll
    for (int i = 0; i < 4; ++i)
#pragma unroll
        for (int j = 0; j < 4; ++j) acc[i][j] = fzero;

    const int p0 = tid, p1 = 256 + tid;
    const bf16_t* a0 = A  + (size_t)(row0 + (p0 & 127)) * K + (p0 >> 7) * 8;
    const bf16_t* a1 = A  + (size_t)(row0 + (p1 & 127)) * K + (p1 >> 7) * 8;
    const bf16_t* b0 = Bt + (size_t)(col0 + (p0 & 127)) * K + (p0 >> 7) * 8;
    const bf16_t* b1 = Bt + (size_t)(col0 + (p1 & 127)) * K + (p1 >> 7) * 8;
    bf16x8* la0 = &Al[wave * 64];
    bf16x8* la1 = &Al[256 + wave * 64];
    bf16x8* lb0 = &Bl[wave * 64];
    bf16x8* lb1 = &Bl[256 + wave * 64];

    for (int kt = 0; kt < K; kt += 32) {
        async_ld16(la0, a0 + kt);
        async_ld16(la1, a1 + kt);
        async_ld16(lb0, b0 + kt);
        async_ld16(lb1, b1 + kt);
        __syncthreads();
        bf16x8 af[4], bfr[4];
#pragma unroll
        for (int mt = 0; mt < 4; ++mt) af[mt]  = Al[g * 128 + wm * 64 + mt * 16 + r];
#pragma unroll
        for (int nt = 0; nt < 4; ++nt) bfr[nt] = Bl[g * 128 + wn * 64 + nt * 16 + r];
#pragma unroll
        for (int mt = 0; mt < 4; ++mt)
#pragma unroll
            for (int nt = 0; nt < 4; ++nt)
                acc[mt][nt] = __builtin_amdgcn_mfma_f32_16x16x32_bf16(
                    af[mt], bfr[nt], acc[mt][nt], 0, 0, 0);
        __syncthreads();
    }

    const int mbase = row0 + wm * 64 + g * 4;
    const int nbase = col0 + wn * 64 + r;
#pragma unroll
    for (int mt = 0; mt < 4; ++mt) {
#pragma unroll
        for (int nt = 0; nt < 4; ++nt) {
#pragma unroll
            for (int e = 0; e < 4; ++e) {
                float val = acc[mt][nt][e];
                const int grow = mbase + mt * 16 + e;
                const int gcol = nbase + nt * 16;
                if constexpr (MODE == 0) {
                    float partner = __shfl_xor(val, 1);
                    const int mat  = gcol >> 10;
                    const int d    = gcol & 1023;
                    const int head = d >> 6;
                    const int dh   = d & 63;
                    const int b    = grow >> 11;
                    const int s    = grow & 2047;
                    const size_t dst = ((size_t)(b * NHEADS + head) * SEQ + s) * DHEAD + dh;
                    if (mat == 2) {
                        vo[dst] = (bf16_t)val;
                    } else {
                        // inv_freq = 10000^(-(dh&~1)/64) ; ln(10000)/64 = 0.14391157
                        const float ang = (float)s * __expf((float)(dh & ~1) * -0.14391157f);
                        float sn, cs;
                        __sincosf(ang, &sn, &cs);
                        const float rv = (dh & 1) ? (partner * sn + val * cs)
                                                  : (val * cs - partner * sn);
                        if (mat == 0) qo[dst] = (bf16_t)(rv * 0.125f);  // fold 1/sqrt(Dh)
                        else          ko[dst] = (bf16_t)rv;
                    }
                } else if constexpr (MODE == 1 || MODE == 3) {
                    const size_t idx = (size_t)grow * D_MODEL + gcol;
                    outf[idx] = res[idx] + val;
                } else { // MODE 2: even combined col = w1, odd = w3
                    float partner = __shfl_xor(val, 1);
                    if (!(lane & 1)) {
                        const float sv = val / (1.f + __expf(-val));
                        gate[(size_t)grow * DFF + (gcol >> 1)] = (bf16_t)(sv * partner);
                    }
                }
            }
        }
    }
}

// ---------------------------------------------------------------------------
// Causal flash attention. q(pre-scaled)/k: [B,H,S,Dh]; vT: [B,H,Dh,S] bf16.
// Grid: (16, B*H), qblk = 15 - bx (heavy-first). 256 thr = 4 waves; each wave
// owns 32 q-rows; K-tile = 128 keys. LDS (64KB exact) in 16B chunks:
//   [0..1023]    K  chunks [ghalf(8)][key(128)]
//   [1024..2047] VT chunks [kchunk(16)][dh(64)]
//   [2048+w*512] P  chunks [kchunk(16)][q(32)] per wave
// All ds_read_b128 start banks = 4*(r&7): conflict-free per 8-lane group.
// ---------------------------------------------------------------------------
__global__ __launch_bounds__(256)
void attn_kernel(const bf16_t* __restrict__ qg, const bf16_t* __restrict__ kg,
                 const bf16_t* __restrict__ vT, bf16_t* __restrict__ ctx)
{
    __shared__ bf16x8 lds[4096];
    const int qblk = (gridDim.x - 1) - blockIdx.x;
    const int bh   = blockIdx.y;
    const int tid  = threadIdx.x;
    const int wave = tid >> 6;
    const int lane = tid & 63;
    const int r = lane & 15, g = lane >> 4;
    const size_t base = (size_t)bh * SEQ * DHEAD;
    const int qw = qblk * 128 + wave * 32;

    bf16x8 qf[2][2];
#pragma unroll
    for (int rt = 0; rt < 2; ++rt)
#pragma unroll
        for (int kh = 0; kh < 2; ++kh)
            qf[rt][kh] = *(const bf16x8*)(qg + base + (size_t)(qw + rt*16 + r) * DHEAD + kh*32 + g*8);

    const f32x4 fzero = {0.f, 0.f, 0.f, 0.f};
    f32x4 O[2][4];
    float mi[2][4], li[2][4];
#pragma unroll
    for (int rt = 0; rt < 2; ++rt)
#pragma unroll
        for (int e = 0; e < 4; ++e) { mi[rt][e] = -1e30f; li[rt][e] = 0.f; }
#pragma unroll
    for (int rt = 0; rt < 2; ++rt)
#pragma unroll
        for (int d = 0; d < 4; ++d) O[rt][d] = fzero;

    bf16_t* const Pb = (bf16_t*)&lds[2048 + wave * 512];

    for (int kb = 0; kb <= qblk; ++kb) {
        const int k0 = kb * 128;
        { // stage K: 1024 chunks [ghalf][key]
            const int ghalf = (wave >> 1);        // + i*2
            const int key   = (wave & 1) * 64 + lane;
            const bf16_t* kp = kg + base + (size_t)(k0 + key) * DHEAD + ghalf * 8;
#pragma unroll
            for (int i = 0; i < 4; ++i)
                async_ld16(&lds[i * 256 + wave * 64], kp + i * 16);
        }
        { // stage VT: 1024 chunks [kchunk][dh]
            const bf16_t* vp = vT + base + (size_t)lane * SEQ + k0 + wave * 8;
#pragma unroll
            for (int i = 0; i < 4; ++i)
                async_ld16(&lds[1024 + i * 256 + wave * 64], vp + i * 32);
        }
        __syncthreads();

        // QK^T: sc[rt][ct], rows qw+rt*16+g*4+e, cols k0+ct*16+r
        f32x4 sc[2][8];
#pragma unroll
        for (int ct = 0; ct < 8; ++ct) {
            const bf16x8 kf0 = lds[g * 128 + ct * 16 + r];
            const bf16x8 kf1 = lds[(4 + g) * 128 + ct * 16 + r];
            sc[0][ct] = __builtin_amdgcn_mfma_f32_16x16x32_bf16(qf[0][0], kf0, fzero, 0, 0, 0);
            sc[0][ct] = __builtin_amdgcn_mfma_f32_16x16x32_bf16(qf[0][1], kf1, sc[0][ct], 0, 0, 0);
            sc[1][ct] = __builtin_amdgcn_mfma_f32_16x16x32_bf16(qf[1][0], kf0, fzero, 0, 0, 0);
            sc[1][ct] = __builtin_amdgcn_mfma_f32_16x16x32_bf16(qf[1][1], kf1, sc[1][ct], 0, 0, 0);
        }
        if (kb == qblk) { // diagonal block: causal mask
#pragma unroll
            for (int rt = 0; rt < 2; ++rt)
#pragma unroll
                for (int ct = 0; ct < 8; ++ct)
#pragma unroll
                    for (int e = 0; e < 4; ++e)
                        if (ct * 16 + r > wave * 32 + rt * 16 + g * 4 + e)
                            sc[rt][ct][e] = -1e30f;
        }
        // online softmax + P write (per-wave LDS, no barrier needed)
#pragma unroll
        for (int rt = 0; rt < 2; ++rt) {
#pragma unroll
            for (int e = 0; e < 4; ++e) {
                float mx = sc[rt][0][e];
#pragma unroll
                for (int ct = 1; ct < 8; ++ct) mx = fmaxf(mx, sc[rt][ct][e]);
#pragma unroll
                for (int d = 1; d < 16; d <<= 1) mx = fmaxf(mx, __shfl_xor(mx, d));
                const float mnew  = fmaxf(mi[rt][e], mx);
                const float alpha = __expf(mi[rt][e] - mnew);
                mi[rt][e] = mnew;
                float pv[8], rs = 0.f;
#pragma unroll
                for (int ct = 0; ct < 8; ++ct) { pv[ct] = __expf(sc[rt][ct][e] - mnew); rs += pv[ct]; }
#pragma unroll
                for (int d = 1; d < 16; d <<= 1) rs += __shfl_xor(rs, d);
                li[rt][e] = li[rt][e] * alpha + rs;
#pragma unroll
                for (int dht = 0; dht < 4; ++dht) O[rt][dht][e] *= alpha;
                const int qlocal = rt * 16 + g * 4 + e;
#pragma unroll
                for (int ct = 0; ct < 8; ++ct) {
                    const int kchunk = ct * 2 + (r >> 3);
                    Pb[(kchunk * 32 + qlocal) * 8 + (r & 7)] = (bf16_t)pv[ct];
                }
            }
        }
        // PV: O[rt][dht] += P[32x128] @ V[128x64]
#pragma unroll
        for (int kt = 0; kt < 4; ++kt) {
            const bf16x8 pf0 = lds[2048 + wave * 512 + (kt * 4 + g) * 32 + r];
            const bf16x8 pf1 = lds[2048 + wave * 512 + (kt * 4 + g) * 32 + 16 + r];
#pragma unroll
            for (int dht = 0; dht < 4; ++dht) {
                const bf16x8 vf = lds[1024 + (kt * 4 + g) * 64 + dht * 16 + r];
                O[0][dht] = __builtin_amdgcn_mfma_f32_16x16x32_bf16(pf0, vf, O[0][dht], 0, 0, 0);
                O[1][dht] = __builtin_amdgcn_mfma_f32_16x16x32_bf16(pf1, vf, O[1][dht], 0, 0, 0);
            }
        }
        __syncthreads();
    }

    const int b = bh >> 4, head = bh & 15;
#pragma unroll
    for (int rt = 0; rt < 2; ++rt) {
#pragma unroll
        for (int e = 0; e < 4; ++e) {
            const float inv = 1.f / li[rt][e];
            const int s = qw + rt * 16 + g * 4 + e;
            bf16_t* op = ctx + ((size_t)(b * SEQ + s)) * D_MODEL + head * DHEAD + r;
#pragma unroll
            for (int dht = 0; dht < 4; ++dht)
                op[dht * 16] = (bf16_t)(O[rt][dht][e] * inv);
        }
    }
}

// ---------------------------------------------------------------------------
extern "C" void kernel_launch(void* const* d_in, const int* in_sizes, int n_in,
                              void* d_out, int out_size, void* d_ws, size_t ws_size,
                              hipStream_t stream)
{
    (void)in_sizes; (void)n_in; (void)out_size; (void)ws_size;
    const float* x  = (const float*)d_in[0];
    const float* g1 = (const float*)d_in[2];
    const float* g2 = (const float*)d_in[3];
    const float* wq = (const float*)d_in[4];
    const float* wk = (const float*)d_in[5];
    const float* wv = (const float*)d_in[6];
    const float* wo = (const float*)d_in[7];
    const float* w1 = (const float*)d_in[8];
    const float* w2 = (const float*)d_in[9];
    const float* w3 = (const float*)d_in[10];
    float* out = (float*)d_out;
    char* ws = (char*)d_ws;
    const size_t MB = 1ull << 20;
    bf16_t* wqkvT = (bf16_t*)(ws + 0);        // 3072 x 1024
    bf16_t* woT   = (bf16_t*)(ws + 6  * MB);  // 1024 x 1024
    bf16_t* w13T  = (bf16_t*)(ws + 8  * MB);  // 8192 x 1024 (w1/w3 interleaved)
    bf16_t* w2T   = (bf16_t*)(ws + 24 * MB);  // 1024 x 4096
    bf16_t* hbuf  = (bf16_t*)(ws + 32 * MB);  // h / h2; reused as vT during attn
    bf16_t* qbuf  = (bf16_t*)(ws + 48 * MB);
    bf16_t* kbuf  = (bf16_t*)(ws + 64 * MB);
    bf16_t* vbuf  = (bf16_t*)(ws + 80 * MB);
    bf16_t* ctx   = (bf16_t*)(ws + 96 * MB);
    bf16_t* gate  = (bf16_t*)(ws + 48 * MB);  // 8192 x 4096, reuses q/k/v/ctx
    bf16_t* vTb   = hbuf;                     // [bh][dh][s], h is dead post-QKV

    dim3 blk(256);
    transpose_cast_kernel<<<dim3(32, 32),  blk, 0, stream>>>(wq, wqkvT,             1024, 1024, 1);
    transpose_cast_kernel<<<dim3(32, 32),  blk, 0, stream>>>(wk, wqkvT + 1024*1024, 1024, 1024, 1);
    transpose_cast_kernel<<<dim3(32, 32),  blk, 0, stream>>>(wv, wqkvT + 2048*1024, 1024, 1024, 1);
    transpose_cast_kernel<<<dim3(32, 32),  blk, 0, stream>>>(wo, woT,               1024, 1024, 1);
    transpose_cast_kernel<<<dim3(128, 32), blk, 0, stream>>>(w1, w13T,              1024, 4096, 2);
    transpose_cast_kernel<<<dim3(128, 32), blk, 0, stream>>>(w3, w13T + 1024,       1024, 4096, 2);
    transpose_cast_kernel<<<dim3(32, 128), blk, 0, stream>>>(w2, w2T,               4096, 1024, 1);

    rmsnorm_kernel<<<dim3(8192), blk, 0, stream>>>(x, g1, hbuf);

    gemm_kernel<0><<<dim3(24, 64), blk, 0, stream>>>(hbuf, wqkvT, 8192, 3072, 1024,
        qbuf, kbuf, vbuf, nullptr, nullptr, nullptr);

    transpose_v_kernel<<<dim3(32, 64), blk, 0, stream>>>(vbuf, vTb);

    attn_kernel<<<dim3(16, 64), blk, 0, stream>>>(qbuf, kbuf, vTb, ctx);

    gemm_kernel<1><<<dim3(8, 64), blk, 0, stream>>>(ctx, woT, 8192, 1024, 1024,
        nullptr, nullptr, nullptr, x, out, nullptr);

    rmsnorm_kernel<<<dim3(8192), blk, 0, stream>>>(out, g2, hbuf);

    gemm_kernel<2><<<dim3(64, 64), blk, 0, stream>>>(hbuf, w13T, 8192, 8192, 1024,
        nullptr, nullptr, nullptr, nullptr, nullptr, gate);

    gemm_kernel<3><<<dim3(8, 64), blk, 0, stream>>>(gate, w2T, 8192, 1024, 4096,
        nullptr, nullptr, nullptr, out, out, nullptr);
}

// Round 3
// 929.427 us; speedup vs baseline: 1.2625x; 1.0184x over previous
//
#include <hip/hip_runtime.h>
#include <hip/hip_bf16.h>
#include <cstdint>
#include <cstddef>

typedef __bf16 bf16_t;
typedef __bf16 bf16x8 __attribute__((ext_vector_type(8)));
typedef __bf16 bf16x4 __attribute__((ext_vector_type(4)));
typedef float  f32x4  __attribute__((ext_vector_type(4)));

#define D_MODEL 1024
#define SEQ     2048
#define NHEADS  16
#define DHEAD   64
#define DFF     4096

// async global->LDS, 16B per lane; lds base must be wave-uniform (dest = base + lane*16)
__device__ __forceinline__ void async_ld16(void* lds, const void* g) {
    __builtin_amdgcn_global_load_lds(
        (__attribute__((address_space(1))) void*)(void*)(g),
        (__attribute__((address_space(3))) void*)(lds), 16, 0, 0);
}

// ---------------------------------------------------------------------------
// fp32 (K x N) -> bf16 transposed; dst row for source col n:
//   (n>>4)*gstride + (n&15) + goff
// gstride=16,goff=0 : plain N x K transpose
// gstride=32,goff=0/16 : 16-col-group interleave (w1/w3 pairing)
// ---------------------------------------------------------------------------
__global__ __launch_bounds__(256)
void transpose_cast_kernel(const float* __restrict__ src, bf16_t* __restrict__ dst,
                           int K, int N, int gstride, int goff)
{
    __shared__ float tile[32][33];
    const int bn = blockIdx.x * 32, bk = blockIdx.y * 32;
    const int tx = threadIdx.x & 31, ty = threadIdx.x >> 5;
#pragma unroll
    for (int i = 0; i < 32; i += 8)
        tile[ty + i][tx] = src[(size_t)(bk + ty + i) * N + bn + tx];
    __syncthreads();
#pragma unroll
    for (int i = 0; i < 32; i += 8) {
        const int n = bn + ty + i, kk = bk + tx;
        const int row = (n >> 4) * gstride + (n & 15) + goff;
        dst[(size_t)row * K + kk] = (bf16_t)tile[tx][ty + i];
    }
}

// ---------------------------------------------------------------------------
// bf16 V [bh][s][dh] -> vT [bh][dh][s], 64x64 tiles
// ---------------------------------------------------------------------------
__global__ __launch_bounds__(256)
void transpose_v_kernel(const bf16_t* __restrict__ v, bf16_t* __restrict__ vt)
{
    __shared__ bf16_t T[64 * 66];   // [dh][s], stride 66
    const int bh = blockIdx.y, s0 = blockIdx.x * 64;
    const int tid = threadIdx.x;
    const size_t vb = (size_t)bh * SEQ * DHEAD;
#pragma unroll
    for (int h = 0; h < 2; ++h) {
        const int s = h * 32 + (tid >> 3), dc = (tid & 7) * 8;
        const bf16x8 vv = *(const bf16x8*)(v + vb + (size_t)(s0 + s) * DHEAD + dc);
#pragma unroll
        for (int j = 0; j < 8; ++j) T[(dc + j) * 66 + s] = vv[j];
    }
    __syncthreads();
    const size_t tb = (size_t)bh * DHEAD * SEQ;
    const uint32_t* Tw = (const uint32_t*)T;
#pragma unroll
    for (int h = 0; h < 2; ++h) {
        const int dh = h * 32 + (tid >> 3), kc = (tid & 7) * 8;
        uint4 o;
        o.x = Tw[dh * 33 + kc / 2 + 0];
        o.y = Tw[dh * 33 + kc / 2 + 1];
        o.z = Tw[dh * 33 + kc / 2 + 2];
        o.w = Tw[dh * 33 + kc / 2 + 3];
        *(uint4*)(vt + tb + (size_t)dh * SEQ + s0 + kc) = o;
    }
}

// ---------------------------------------------------------------------------
// RMSNorm: fp32 row (1024) -> bf16 row
// ---------------------------------------------------------------------------
__global__ __launch_bounds__(256)
void rmsnorm_kernel(const float* __restrict__ x, const float* __restrict__ gw,
                    bf16_t* __restrict__ out)
{
    const int row = blockIdx.x, tid = threadIdx.x;
    const float4 v = ((const float4*)(x + (size_t)row * D_MODEL))[tid];
    float ss = v.x*v.x + v.y*v.y + v.z*v.z + v.w*v.w;
#pragma unroll
    for (int d = 1; d < 64; d <<= 1) ss += __shfl_xor(ss, d);
    __shared__ float red[4];
    if ((tid & 63) == 0) red[tid >> 6] = ss;
    __syncthreads();
    const float tot = red[0] + red[1] + red[2] + red[3];
    const float sc = rsqrtf(tot * (1.f / D_MODEL) + 1e-5f);
    const float4 gv = ((const float4*)gw)[tid];
    bf16x4 o;
    o[0] = (bf16_t)(v.x * sc * gv.x);
    o[1] = (bf16_t)(v.y * sc * gv.y);
    o[2] = (bf16_t)(v.z * sc * gv.z);
    o[3] = (bf16_t)(v.w * sc * gv.w);
    ((bf16x4*)(out + (size_t)row * D_MODEL))[tid] = o;
}

// ---------------------------------------------------------------------------
// GEMM: C[M,N] = A[M,K] (bf16 row-major) @ Bt[N,K]^T
// XCD-band swizzle: linear block id -> xcd = i&7 owns col-tile band of
// width gridDim.x/8 -> per-XCD B working set fits 4MB L2.
// MODE 0: QKV + RoPE -> q(*0.125)/k/v [B,H,S,Dh] bf16
// MODE 1: y = res + C  (fp32 out)
// MODE 2: gate = silu(C_w1) * C_w3 (w1/w3 in 16-col groups) -> bf16
// MODE 3: out = res + C (fp32, res may alias outf)
// ---------------------------------------------------------------------------
template <int MODE>
__global__ __launch_bounds__(256)
void gemm_kernel(const bf16_t* __restrict__ A, const bf16_t* __restrict__ Bt,
                 int M, int N, int K,
                 bf16_t* __restrict__ qo, bf16_t* __restrict__ ko, bf16_t* __restrict__ vo,
                 const float* res, float* outf, bf16_t* __restrict__ gate)
{
    __shared__ bf16x8 Al[512];
    __shared__ bf16x8 Bl[512];
    const int tid  = threadIdx.x;
    const int wave = tid >> 6;
    const int lane = tid & 63;
    const int r    = lane & 15;
    const int g    = lane >> 4;
    const int wm   = wave >> 1;
    const int wn   = wave & 1;

    // XCD-band block swizzle
    int bx, by;
    {
        const int nbx = gridDim.x;
        const int i = blockIdx.x + nbx * blockIdx.y;
        if ((nbx & 7) == 0 || nbx >= 8) {
            const int band = nbx >> 3;
            const int xcd = i & 7, j = i >> 3;
            bx = xcd * band + (j % band);
            by = j / band;
        } else { bx = blockIdx.x; by = blockIdx.y; }
    }
    const int row0 = by * 128;
    const int col0 = bx * 128;

    const f32x4 fzero = {0.f, 0.f, 0.f, 0.f};
    f32x4 acc[4][4];
#pragma unroll
    for (int i = 0; i < 4; ++i)
#pragma unroll
        for (int j = 0; j < 4; ++j) acc[i][j] = fzero;

    const int p0 = tid, p1 = 256 + tid;
    const bf16_t* a0 = A  + (size_t)(row0 + (p0 & 127)) * K + (p0 >> 7) * 8;
    const bf16_t* a1 = A  + (size_t)(row0 + (p1 & 127)) * K + (p1 >> 7) * 8;
    const bf16_t* b0 = Bt + (size_t)(col0 + (p0 & 127)) * K + (p0 >> 7) * 8;
    const bf16_t* b1 = Bt + (size_t)(col0 + (p1 & 127)) * K + (p1 >> 7) * 8;
    bf16x8* la0 = &Al[wave * 64];
    bf16x8* la1 = &Al[256 + wave * 64];
    bf16x8* lb0 = &Bl[wave * 64];
    bf16x8* lb1 = &Bl[256 + wave * 64];

    for (int kt = 0; kt < K; kt += 32) {
        async_ld16(la0, a0 + kt);
        async_ld16(la1, a1 + kt);
        async_ld16(lb0, b0 + kt);
        async_ld16(lb1, b1 + kt);
        __syncthreads();
        bf16x8 af[4], bfr[4];
#pragma unroll
        for (int mt = 0; mt < 4; ++mt) af[mt]  = Al[g * 128 + wm * 64 + mt * 16 + r];
#pragma unroll
        for (int nt = 0; nt < 4; ++nt) bfr[nt] = Bl[g * 128 + wn * 64 + nt * 16 + r];
#pragma unroll
        for (int mt = 0; mt < 4; ++mt)
#pragma unroll
            for (int nt = 0; nt < 4; ++nt)
                acc[mt][nt] = __builtin_amdgcn_mfma_f32_16x16x32_bf16(
                    af[mt], bfr[nt], acc[mt][nt], 0, 0, 0);
        __syncthreads();
    }

    const int mbase = row0 + wm * 64 + g * 4;
    const int nbase = col0 + wn * 64 + r;

    if constexpr (MODE == 2) {
        // 16-col-group interleave: nt even = w1, nt odd = w3, same out cols.
#pragma unroll
        for (int np = 0; np < 2; ++np) {
            const int gc = (col0 >> 1) + wn * 32 + np * 16 + r;
#pragma unroll
            for (int mt = 0; mt < 4; ++mt) {
#pragma unroll
                for (int e = 0; e < 4; ++e) {
                    const float v1 = acc[mt][2 * np][e];
                    const float v3 = acc[mt][2 * np + 1][e];
                    const float sv = v1 * __builtin_amdgcn_rcpf(1.f + __expf(-v1));
                    const int grow = mbase + mt * 16 + e;
                    gate[(size_t)grow * DFF + gc] = (bf16_t)(sv * v3);
                }
            }
        }
    } else if constexpr (MODE == 0) {
#pragma unroll
        for (int nt = 0; nt < 4; ++nt) {
            const int gcol = nbase + nt * 16;
            const int mat  = gcol >> 10;
            const int d    = gcol & 1023;
            const int head = d >> 6;
            const int dh   = d & 63;
            // inv_freq = 10000^(-(dh&~1)/64); ln(10000)/64 = 0.14391157
            const float invf = __expf((float)(dh & ~1) * -0.14391157f);
            const size_t hb = (size_t)head * SEQ * DHEAD + dh;
#pragma unroll
            for (int mt = 0; mt < 4; ++mt) {
#pragma unroll
                for (int e = 0; e < 4; ++e) {
                    const float val = acc[mt][nt][e];
                    const float partner = __shfl_xor(val, 1);
                    const int grow = mbase + mt * 16 + e;
                    const int b = grow >> 11;
                    const int s = grow & 2047;
                    const size_t dst = (size_t)b * NHEADS * SEQ * DHEAD + hb + (size_t)s * DHEAD;
                    if (mat == 2) {
                        vo[dst] = (bf16_t)val;
                    } else {
                        float sn, cs;
                        __sincosf((float)s * invf, &sn, &cs);
                        const float rv = (dh & 1) ? (partner * sn + val * cs)
                                                  : (val * cs - partner * sn);
                        if (mat == 0) qo[dst] = (bf16_t)(rv * 0.125f);  // fold 1/sqrt(Dh)
                        else          ko[dst] = (bf16_t)rv;
                    }
                }
            }
        }
    } else { // MODE 1 / 3
#pragma unroll
        for (int mt = 0; mt < 4; ++mt) {
#pragma unroll
            for (int nt = 0; nt < 4; ++nt) {
#pragma unroll
                for (int e = 0; e < 4; ++e) {
                    const int grow = mbase + mt * 16 + e;
                    const int gcol = nbase + nt * 16;
                    const size_t idx = (size_t)grow * D_MODEL + gcol;
                    outf[idx] = res[idx] + acc[mt][nt][e];
                }
            }
        }
    }
}

// ---------------------------------------------------------------------------
// Causal flash attention. q(pre-scaled)/k: [B,H,S,Dh]; vT: [B,H,Dh,S] bf16.
// Grid: (16, B*H), qblk = 15 - bx (heavy-first). 4 waves x 32 q-rows;
// K-tile = 128 keys. LDS 64KB in 16B chunks, conflict-free reads.
// ---------------------------------------------------------------------------
__global__ __launch_bounds__(256)
void attn_kernel(const bf16_t* __restrict__ qg, const bf16_t* __restrict__ kg,
                 const bf16_t* __restrict__ vT, bf16_t* __restrict__ ctx)
{
    __shared__ bf16x8 lds[4096];
    const int qblk = (gridDim.x - 1) - blockIdx.x;
    const int bh   = blockIdx.y;
    const int tid  = threadIdx.x;
    const int wave = tid >> 6;
    const int lane = tid & 63;
    const int r = lane & 15, g = lane >> 4;
    const size_t base = (size_t)bh * SEQ * DHEAD;
    const int qw = qblk * 128 + wave * 32;

    bf16x8 qf[2][2];
#pragma unroll
    for (int rt = 0; rt < 2; ++rt)
#pragma unroll
        for (int kh = 0; kh < 2; ++kh)
            qf[rt][kh] = *(const bf16x8*)(qg + base + (size_t)(qw + rt*16 + r) * DHEAD + kh*32 + g*8);

    const f32x4 fzero = {0.f, 0.f, 0.f, 0.f};
    f32x4 O[2][4];
    float mi[2][4], li[2][4];
#pragma unroll
    for (int rt = 0; rt < 2; ++rt)
#pragma unroll
        for (int e = 0; e < 4; ++e) { mi[rt][e] = -1e30f; li[rt][e] = 0.f; }
#pragma unroll
    for (int rt = 0; rt < 2; ++rt)
#pragma unroll
        for (int d = 0; d < 4; ++d) O[rt][d] = fzero;

    bf16_t* const Pb = (bf16_t*)&lds[2048 + wave * 512];

    for (int kb = 0; kb <= qblk; ++kb) {
        const int k0 = kb * 128;
        { // stage K: 1024 chunks [ghalf][key]
            const int ghalf = (wave >> 1);
            const int key   = (wave & 1) * 64 + lane;
            const bf16_t* kp = kg + base + (size_t)(k0 + key) * DHEAD + ghalf * 8;
#pragma unroll
            for (int i = 0; i < 4; ++i)
                async_ld16(&lds[i * 256 + wave * 64], kp + i * 16);
        }
        { // stage VT: 1024 chunks [kchunk][dh]
            const bf16_t* vp = vT + base + (size_t)lane * SEQ + k0 + wave * 8;
#pragma unroll
            for (int i = 0; i < 4; ++i)
                async_ld16(&lds[1024 + i * 256 + wave * 64], vp + i * 32);
        }
        __syncthreads();

        f32x4 sc[2][8];
#pragma unroll
        for (int ct = 0; ct < 8; ++ct) {
            const bf16x8 kf0 = lds[g * 128 + ct * 16 + r];
            const bf16x8 kf1 = lds[(4 + g) * 128 + ct * 16 + r];
            sc[0][ct] = __builtin_amdgcn_mfma_f32_16x16x32_bf16(qf[0][0], kf0, fzero, 0, 0, 0);
            sc[0][ct] = __builtin_amdgcn_mfma_f32_16x16x32_bf16(qf[0][1], kf1, sc[0][ct], 0, 0, 0);
            sc[1][ct] = __builtin_amdgcn_mfma_f32_16x16x32_bf16(qf[1][0], kf0, fzero, 0, 0, 0);
            sc[1][ct] = __builtin_amdgcn_mfma_f32_16x16x32_bf16(qf[1][1], kf1, sc[1][ct], 0, 0, 0);
        }
        if (kb == qblk) { // diagonal block: causal mask
#pragma unroll
            for (int rt = 0; rt < 2; ++rt)
#pragma unroll
                for (int ct = 0; ct < 8; ++ct)
#pragma unroll
                    for (int e = 0; e < 4; ++e)
                        if (ct * 16 + r > wave * 32 + rt * 16 + g * 4 + e)
                            sc[rt][ct][e] = -1e30f;
        }
#pragma unroll
        for (int rt = 0; rt < 2; ++rt) {
#pragma unroll
            for (int e = 0; e < 4; ++e) {
                float mx = sc[rt][0][e];
#pragma unroll
                for (int ct = 1; ct < 8; ++ct) mx = fmaxf(mx, sc[rt][ct][e]);
#pragma unroll
                for (int d = 1; d < 16; d <<= 1) mx = fmaxf(mx, __shfl_xor(mx, d));
                const float mnew  = fmaxf(mi[rt][e], mx);
                const float alpha = __expf(mi[rt][e] - mnew);
                mi[rt][e] = mnew;
                float pv[8], rs = 0.f;
#pragma unroll
                for (int ct = 0; ct < 8; ++ct) { pv[ct] = __expf(sc[rt][ct][e] - mnew); rs += pv[ct]; }
#pragma unroll
                for (int d = 1; d < 16; d <<= 1) rs += __shfl_xor(rs, d);
                li[rt][e] = li[rt][e] * alpha + rs;
#pragma unroll
                for (int dht = 0; dht < 4; ++dht) O[rt][dht][e] *= alpha;
                const int qlocal = rt * 16 + g * 4 + e;
#pragma unroll
                for (int ct = 0; ct < 8; ++ct) {
                    const int kchunk = ct * 2 + (r >> 3);
                    Pb[(kchunk * 32 + qlocal) * 8 + (r & 7)] = (bf16_t)pv[ct];
                }
            }
        }
#pragma unroll
        for (int kt = 0; kt < 4; ++kt) {
            const bf16x8 pf0 = lds[2048 + wave * 512 + (kt * 4 + g) * 32 + r];
            const bf16x8 pf1 = lds[2048 + wave * 512 + (kt * 4 + g) * 32 + 16 + r];
#pragma unroll
            for (int dht = 0; dht < 4; ++dht) {
                const bf16x8 vf = lds[1024 + (kt * 4 + g) * 64 + dht * 16 + r];
                O[0][dht] = __builtin_amdgcn_mfma_f32_16x16x32_bf16(pf0, vf, O[0][dht], 0, 0, 0);
                O[1][dht] = __builtin_amdgcn_mfma_f32_16x16x32_bf16(pf1, vf, O[1][dht], 0, 0, 0);
            }
        }
        __syncthreads();
    }

    const int b = bh >> 4, head = bh & 15;
#pragma unroll
    for (int rt = 0; rt < 2; ++rt) {
#pragma unroll
        for (int e = 0; e < 4; ++e) {
            const float inv = __builtin_amdgcn_rcpf(li[rt][e]);
            const int s = qw + rt * 16 + g * 4 + e;
            bf16_t* op = ctx + ((size_t)(b * SEQ + s)) * D_MODEL + head * DHEAD + r;
#pragma unroll
            for (int dht = 0; dht < 4; ++dht)
                op[dht * 16] = (bf16_t)(O[rt][dht][e] * inv);
        }
    }
}

// ---------------------------------------------------------------------------
extern "C" void kernel_launch(void* const* d_in, const int* in_sizes, int n_in,
                              void* d_out, int out_size, void* d_ws, size_t ws_size,
                              hipStream_t stream)
{
    (void)in_sizes; (void)n_in; (void)out_size; (void)ws_size;
    const float* x  = (const float*)d_in[0];
    const float* g1 = (const float*)d_in[2];
    const float* g2 = (const float*)d_in[3];
    const float* wq = (const float*)d_in[4];
    const float* wk = (const float*)d_in[5];
    const float* wv = (const float*)d_in[6];
    const float* wo = (const float*)d_in[7];
    const float* w1 = (const float*)d_in[8];
    const float* w2 = (const float*)d_in[9];
    const float* w3 = (const float*)d_in[10];
    float* out = (float*)d_out;
    char* ws = (char*)d_ws;
    const size_t MB = 1ull << 20;
    bf16_t* wqkvT = (bf16_t*)(ws + 0);        // 3072 x 1024
    bf16_t* woT   = (bf16_t*)(ws + 6  * MB);  // 1024 x 1024
    bf16_t* w13T  = (bf16_t*)(ws + 8  * MB);  // 8192 x 1024 (16-col-group ilv)
    bf16_t* w2T   = (bf16_t*)(ws + 24 * MB);  // 1024 x 4096
    bf16_t* hbuf  = (bf16_t*)(ws + 32 * MB);  // h / h2; reused as vT during attn
    bf16_t* qbuf  = (bf16_t*)(ws + 48 * MB);
    bf16_t* kbuf  = (bf16_t*)(ws + 64 * MB);
    bf16_t* vbuf  = (bf16_t*)(ws + 80 * MB);
    bf16_t* ctx   = (bf16_t*)(ws + 96 * MB);
    bf16_t* gate  = (bf16_t*)(ws + 48 * MB);  // 8192 x 4096, reuses q/k/v/ctx
    bf16_t* vTb   = hbuf;                     // [bh][dh][s], h dead post-QKV

    dim3 blk(256);
    transpose_cast_kernel<<<dim3(32, 32),  blk, 0, stream>>>(wq, wqkvT,             1024, 1024, 16, 0);
    transpose_cast_kernel<<<dim3(32, 32),  blk, 0, stream>>>(wk, wqkvT + 1024*1024, 1024, 1024, 16, 0);
    transpose_cast_kernel<<<dim3(32, 32),  blk, 0, stream>>>(wv, wqkvT + 2048*1024, 1024, 1024, 16, 0);
    transpose_cast_kernel<<<dim3(32, 32),  blk, 0, stream>>>(wo, woT,               1024, 1024, 16, 0);
    transpose_cast_kernel<<<dim3(128, 32), blk, 0, stream>>>(w1, w13T,              1024, 4096, 32, 0);
    transpose_cast_kernel<<<dim3(128, 32), blk, 0, stream>>>(w3, w13T,              1024, 4096, 32, 16);
    transpose_cast_kernel<<<dim3(32, 128), blk, 0, stream>>>(w2, w2T,               4096, 1024, 16, 0);

    rmsnorm_kernel<<<dim3(8192), blk, 0, stream>>>(x, g1, hbuf);

    gemm_kernel<0><<<dim3(24, 64), blk, 0, stream>>>(hbuf, wqkvT, 8192, 3072, 1024,
        qbuf, kbuf, vbuf, nullptr, nullptr, nullptr);

    transpose_v_kernel<<<dim3(32, 64), blk, 0, stream>>>(vbuf, vTb);

    attn_kernel<<<dim3(16, 64), blk, 0, stream>>>(qbuf, kbuf, vTb, ctx);

    gemm_kernel<1><<<dim3(8, 64), blk, 0, stream>>>(ctx, woT, 8192, 1024, 1024,
        nullptr, nullptr, nullptr, x, out, nullptr);

    rmsnorm_kernel<<<dim3(8192), blk, 0, stream>>>(out, g2, hbuf);

    gemm_kernel<2><<<dim3(64, 64), blk, 0, stream>>>(hbuf, w13T, 8192, 8192, 1024,
        nullptr, nullptr, nullptr, nullptr, nullptr, gate);

    gemm_kernel<3><<<dim3(8, 64), blk, 0, stream>>>(gate, w2T, 8192, 1024, 4096,
        nullptr, nullptr, nullptr, out, out, nullptr);
}

// Round 4
// 910.770 us; speedup vs baseline: 1.2884x; 1.0205x over previous
//
#include <hip/hip_runtime.h>
#include <hip/hip_bf16.h>
#include <cstdint>
#include <cstddef>

typedef __bf16 bf16_t;
typedef __bf16 bf16x8 __attribute__((ext_vector_type(8)));
typedef __bf16 bf16x4 __attribute__((ext_vector_type(4)));
typedef float  f32x4  __attribute__((ext_vector_type(4)));

#define D_MODEL 1024
#define SEQ     2048
#define NHEADS  16
#define DHEAD   64
#define DFF     4096

// async global->LDS, 16B per lane; lds base must be wave-uniform (dest = base + lane*16)
__device__ __forceinline__ void async_ld16(void* lds, const void* g) {
    __builtin_amdgcn_global_load_lds(
        (__attribute__((address_space(1))) void*)(void*)(g),
        (__attribute__((address_space(3))) void*)(lds), 16, 0, 0);
}

// ---------------------------------------------------------------------------
// fp32 (K x N) -> bf16 transposed; dst row for source col n:
//   (n>>4)*gstride + (n&15) + goff
// gstride=16,goff=0 : plain N x K transpose
// gstride=32,goff=0/16 : 16-col-group interleave (w1/w3 pairing)
// ---------------------------------------------------------------------------
__global__ __launch_bounds__(256)
void transpose_cast_kernel(const float* __restrict__ src, bf16_t* __restrict__ dst,
                           int K, int N, int gstride, int goff)
{
    __shared__ float tile[32][33];
    const int bn = blockIdx.x * 32, bk = blockIdx.y * 32;
    const int tx = threadIdx.x & 31, ty = threadIdx.x >> 5;
#pragma unroll
    for (int i = 0; i < 32; i += 8)
        tile[ty + i][tx] = src[(size_t)(bk + ty + i) * N + bn + tx];
    __syncthreads();
#pragma unroll
    for (int i = 0; i < 32; i += 8) {
        const int n = bn + ty + i, kk = bk + tx;
        const int row = (n >> 4) * gstride + (n & 15) + goff;
        dst[(size_t)row * K + kk] = (bf16_t)tile[tx][ty + i];
    }
}

// ---------------------------------------------------------------------------
// bf16 V [bh][s][dh] -> vT [bh][dh][s], 64x64 tiles
// ---------------------------------------------------------------------------
__global__ __launch_bounds__(256)
void transpose_v_kernel(const bf16_t* __restrict__ v, bf16_t* __restrict__ vt)
{
    __shared__ bf16_t T[64 * 66];   // [dh][s], stride 66
    const int bh = blockIdx.y, s0 = blockIdx.x * 64;
    const int tid = threadIdx.x;
    const size_t vb = (size_t)bh * SEQ * DHEAD;
#pragma unroll
    for (int h = 0; h < 2; ++h) {
        const int s = h * 32 + (tid >> 3), dc = (tid & 7) * 8;
        const bf16x8 vv = *(const bf16x8*)(v + vb + (size_t)(s0 + s) * DHEAD + dc);
#pragma unroll
        for (int j = 0; j < 8; ++j) T[(dc + j) * 66 + s] = vv[j];
    }
    __syncthreads();
    const size_t tb = (size_t)bh * DHEAD * SEQ;
    const uint32_t* Tw = (const uint32_t*)T;
#pragma unroll
    for (int h = 0; h < 2; ++h) {
        const int dh = h * 32 + (tid >> 3), kc = (tid & 7) * 8;
        uint4 o;
        o.x = Tw[dh * 33 + kc / 2 + 0];
        o.y = Tw[dh * 33 + kc / 2 + 1];
        o.z = Tw[dh * 33 + kc / 2 + 2];
        o.w = Tw[dh * 33 + kc / 2 + 3];
        *(uint4*)(vt + tb + (size_t)dh * SEQ + s0 + kc) = o;
    }
}

// ---------------------------------------------------------------------------
// RMSNorm: fp32 row (1024) -> bf16 row
// ---------------------------------------------------------------------------
__global__ __launch_bounds__(256)
void rmsnorm_kernel(const float* __restrict__ x, const float* __restrict__ gw,
                    bf16_t* __restrict__ out)
{
    const int row = blockIdx.x, tid = threadIdx.x;
    const float4 v = ((const float4*)(x + (size_t)row * D_MODEL))[tid];
    float ss = v.x*v.x + v.y*v.y + v.z*v.z + v.w*v.w;
#pragma unroll
    for (int d = 1; d < 64; d <<= 1) ss += __shfl_xor(ss, d);
    __shared__ float red[4];
    if ((tid & 63) == 0) red[tid >> 6] = ss;
    __syncthreads();
    const float tot = red[0] + red[1] + red[2] + red[3];
    const float sc = rsqrtf(tot * (1.f / D_MODEL) + 1e-5f);
    const float4 gv = ((const float4*)gw)[tid];
    bf16x4 o;
    o[0] = (bf16_t)(v.x * sc * gv.x);
    o[1] = (bf16_t)(v.y * sc * gv.y);
    o[2] = (bf16_t)(v.z * sc * gv.z);
    o[3] = (bf16_t)(v.w * sc * gv.w);
    ((bf16x4*)(out + (size_t)row * D_MODEL))[tid] = o;
}

// ---------------------------------------------------------------------------
// GEMM: C[M,N] = A[M,K] (bf16 row-major) @ Bt[N,K]^T.  BK=64: 32 MFMA +
// 16 ds_read_b128 between barriers (halved drain count vs BK=32).
// LDS chunk layout [kchunk][row] matches global_load_lds lane order.
// XCD-band swizzle keeps per-XCD B working set inside 4MB L2.
// MODE 0: QKV + RoPE -> q(*0.125)/k/v [B,H,S,Dh] bf16
// MODE 1: y = res + C  (fp32 out)
// MODE 2: gate = silu(C_w1) * C_w3 (w1/w3 in 16-col groups) -> bf16
// MODE 3: out = res + C (fp32, res may alias outf)
// ---------------------------------------------------------------------------
template <int MODE>
__global__ __launch_bounds__(256, 3)
void gemm_kernel(const bf16_t* __restrict__ A, const bf16_t* __restrict__ Bt,
                 int M, int N, int K,
                 bf16_t* __restrict__ qo, bf16_t* __restrict__ ko, bf16_t* __restrict__ vo,
                 const float* res, float* outf, bf16_t* __restrict__ gate)
{
    __shared__ bf16x8 Al[1024];   // 16 KB: 128 rows x 64 k
    __shared__ bf16x8 Bl[1024];   // 16 KB
    const int tid  = threadIdx.x;
    const int wave = tid >> 6;
    const int lane = tid & 63;
    const int r    = lane & 15;
    const int g    = lane >> 4;
    const int wm   = wave >> 1;
    const int wn   = wave & 1;

    // XCD-band block swizzle
    int bx, by;
    {
        const int nbx = gridDim.x;
        const int i = blockIdx.x + nbx * blockIdx.y;
        if (nbx >= 8) {
            const int band = nbx >> 3;
            const int xcd = i & 7, j = i >> 3;
            bx = xcd * band + (j % band);
            by = j / band;
        } else { bx = blockIdx.x; by = blockIdx.y; }
    }
    const int row0 = by * 128;
    const int col0 = bx * 128;

    const f32x4 fzero = {0.f, 0.f, 0.f, 0.f};
    f32x4 acc[4][4];
#pragma unroll
    for (int i = 0; i < 4; ++i)
#pragma unroll
        for (int j = 0; j < 4; ++j) acc[i][j] = fzero;

    // staging: instr i covers chunk c = i*256 + tid -> kchunk = c>>7 = i*2+(tid>>7),
    // row = c&127; LDS idx = c  (layout [kchunk(8)][row(128)])
    const bf16_t* a0 = A  + (size_t)(row0 + (tid & 127)) * K + (tid >> 7) * 8;
    const bf16_t* b0 = Bt + (size_t)(col0 + (tid & 127)) * K + (tid >> 7) * 8;

    for (int kt = 0; kt < K; kt += 64) {
#pragma unroll
        for (int i = 0; i < 4; ++i)
            async_ld16(&Al[i * 256 + wave * 64], a0 + kt + i * 16);
#pragma unroll
        for (int i = 0; i < 4; ++i)
            async_ld16(&Bl[i * 256 + wave * 64], b0 + kt + i * 16);
        __syncthreads();
#pragma unroll
        for (int s = 0; s < 2; ++s) {
            bf16x8 af[4], bfr[4];
#pragma unroll
            for (int mt = 0; mt < 4; ++mt) af[mt]  = Al[(s * 4 + g) * 128 + wm * 64 + mt * 16 + r];
#pragma unroll
            for (int nt = 0; nt < 4; ++nt) bfr[nt] = Bl[(s * 4 + g) * 128 + wn * 64 + nt * 16 + r];
#pragma unroll
            for (int mt = 0; mt < 4; ++mt)
#pragma unroll
                for (int nt = 0; nt < 4; ++nt)
                    acc[mt][nt] = __builtin_amdgcn_mfma_f32_16x16x32_bf16(
                        af[mt], bfr[nt], acc[mt][nt], 0, 0, 0);
        }
        __syncthreads();
    }

    const int mbase = row0 + wm * 64 + g * 4;
    const int nbase = col0 + wn * 64 + r;

    if constexpr (MODE == 2) {
        // 16-col-group interleave: nt even = w1, nt odd = w3, same out cols.
#pragma unroll
        for (int np = 0; np < 2; ++np) {
            const int gc = (col0 >> 1) + wn * 32 + np * 16 + r;
#pragma unroll
            for (int mt = 0; mt < 4; ++mt) {
#pragma unroll
                for (int e = 0; e < 4; ++e) {
                    const float v1 = acc[mt][2 * np][e];
                    const float v3 = acc[mt][2 * np + 1][e];
                    const float sv = v1 * __builtin_amdgcn_rcpf(1.f + __expf(-v1));
                    const int grow = mbase + mt * 16 + e;
                    gate[(size_t)grow * DFF + gc] = (bf16_t)(sv * v3);
                }
            }
        }
    } else if constexpr (MODE == 0) {
#pragma unroll
        for (int nt = 0; nt < 4; ++nt) {
            const int gcol = nbase + nt * 16;
            const int mat  = gcol >> 10;
            const int d    = gcol & 1023;
            const int head = d >> 6;
            const int dh   = d & 63;
            // inv_freq = 10000^(-(dh&~1)/64); ln(10000)/64 = 0.14391157
            const float invf = __expf((float)(dh & ~1) * -0.14391157f);
            const size_t hb = (size_t)head * SEQ * DHEAD + dh;
#pragma unroll
            for (int mt = 0; mt < 4; ++mt) {
#pragma unroll
                for (int e = 0; e < 4; ++e) {
                    const float val = acc[mt][nt][e];
                    const float partner = __shfl_xor(val, 1);
                    const int grow = mbase + mt * 16 + e;
                    const int b = grow >> 11;
                    const int s = grow & 2047;
                    const size_t dst = (size_t)b * NHEADS * SEQ * DHEAD + hb + (size_t)s * DHEAD;
                    if (mat == 2) {
                        vo[dst] = (bf16_t)val;
                    } else {
                        float sn, cs;
                        __sincosf((float)s * invf, &sn, &cs);
                        const float rv = (dh & 1) ? (partner * sn + val * cs)
                                                  : (val * cs - partner * sn);
                        if (mat == 0) qo[dst] = (bf16_t)(rv * 0.125f);  // fold 1/sqrt(Dh)
                        else          ko[dst] = (bf16_t)rv;
                    }
                }
            }
        }
    } else { // MODE 1 / 3
#pragma unroll
        for (int mt = 0; mt < 4; ++mt) {
#pragma unroll
            for (int nt = 0; nt < 4; ++nt) {
#pragma unroll
                for (int e = 0; e < 4; ++e) {
                    const int grow = mbase + mt * 16 + e;
                    const int gcol = nbase + nt * 16;
                    const size_t idx = (size_t)grow * D_MODEL + gcol;
                    outf[idx] = res[idx] + acc[mt][nt][e];
                }
            }
        }
    }
}

// ---------------------------------------------------------------------------
// Causal flash attention. q(pre-scaled)/k: [B,H,S,Dh]; vT: [B,H,Dh,S] bf16.
// Grid: (16, B*H), qblk = 15 - bx (heavy-first). 4 waves x 32 q-rows;
// K-tile = 128 keys. LDS 64KB in 16B chunks, conflict-free reads.
// ---------------------------------------------------------------------------
__global__ __launch_bounds__(256)
void attn_kernel(const bf16_t* __restrict__ qg, const bf16_t* __restrict__ kg,
                 const bf16_t* __restrict__ vT, bf16_t* __restrict__ ctx)
{
    __shared__ bf16x8 lds[4096];
    const int qblk = (gridDim.x - 1) - blockIdx.x;
    const int bh   = blockIdx.y;
    const int tid  = threadIdx.x;
    const int wave = tid >> 6;
    const int lane = tid & 63;
    const int r = lane & 15, g = lane >> 4;
    const size_t base = (size_t)bh * SEQ * DHEAD;
    const int qw = qblk * 128 + wave * 32;

    bf16x8 qf[2][2];
#pragma unroll
    for (int rt = 0; rt < 2; ++rt)
#pragma unroll
        for (int kh = 0; kh < 2; ++kh)
            qf[rt][kh] = *(const bf16x8*)(qg + base + (size_t)(qw + rt*16 + r) * DHEAD + kh*32 + g*8);

    const f32x4 fzero = {0.f, 0.f, 0.f, 0.f};
    f32x4 O[2][4];
    float mi[2][4], li[2][4];
#pragma unroll
    for (int rt = 0; rt < 2; ++rt)
#pragma unroll
        for (int e = 0; e < 4; ++e) { mi[rt][e] = -1e30f; li[rt][e] = 0.f; }
#pragma unroll
    for (int rt = 0; rt < 2; ++rt)
#pragma unroll
        for (int d = 0; d < 4; ++d) O[rt][d] = fzero;

    bf16_t* const Pb = (bf16_t*)&lds[2048 + wave * 512];

    for (int kb = 0; kb <= qblk; ++kb) {
        const int k0 = kb * 128;
        { // stage K: 1024 chunks [ghalf][key]
            const int ghalf = (wave >> 1);
            const int key   = (wave & 1) * 64 + lane;
            const bf16_t* kp = kg + base + (size_t)(k0 + key) * DHEAD + ghalf * 8;
#pragma unroll
            for (int i = 0; i < 4; ++i)
                async_ld16(&lds[i * 256 + wave * 64], kp + i * 16);
        }
        { // stage VT: 1024 chunks [kchunk][dh]
            const bf16_t* vp = vT + base + (size_t)lane * SEQ + k0 + wave * 8;
#pragma unroll
            for (int i = 0; i < 4; ++i)
                async_ld16(&lds[1024 + i * 256 + wave * 64], vp + i * 32);
        }
        __syncthreads();

        f32x4 sc[2][8];
#pragma unroll
        for (int ct = 0; ct < 8; ++ct) {
            const bf16x8 kf0 = lds[g * 128 + ct * 16 + r];
            const bf16x8 kf1 = lds[(4 + g) * 128 + ct * 16 + r];
            sc[0][ct] = __builtin_amdgcn_mfma_f32_16x16x32_bf16(qf[0][0], kf0, fzero, 0, 0, 0);
            sc[0][ct] = __builtin_amdgcn_mfma_f32_16x16x32_bf16(qf[0][1], kf1, sc[0][ct], 0, 0, 0);
            sc[1][ct] = __builtin_amdgcn_mfma_f32_16x16x32_bf16(qf[1][0], kf0, fzero, 0, 0, 0);
            sc[1][ct] = __builtin_amdgcn_mfma_f32_16x16x32_bf16(qf[1][1], kf1, sc[1][ct], 0, 0, 0);
        }
        if (kb == qblk) { // diagonal block: causal mask
#pragma unroll
            for (int rt = 0; rt < 2; ++rt)
#pragma unroll
                for (int ct = 0; ct < 8; ++ct)
#pragma unroll
                    for (int e = 0; e < 4; ++e)
                        if (ct * 16 + r > wave * 32 + rt * 16 + g * 4 + e)
                            sc[rt][ct][e] = -1e30f;
        }
#pragma unroll
        for (int rt = 0; rt < 2; ++rt) {
#pragma unroll
            for (int e = 0; e < 4; ++e) {
                float mx = sc[rt][0][e];
#pragma unroll
                for (int ct = 1; ct < 8; ++ct) mx = fmaxf(mx, sc[rt][ct][e]);
#pragma unroll
                for (int d = 1; d < 16; d <<= 1) mx = fmaxf(mx, __shfl_xor(mx, d));
                const float mnew  = fmaxf(mi[rt][e], mx);
                const float alpha = __expf(mi[rt][e] - mnew);
                mi[rt][e] = mnew;
                float pv[8], rs = 0.f;
#pragma unroll
                for (int ct = 0; ct < 8; ++ct) { pv[ct] = __expf(sc[rt][ct][e] - mnew); rs += pv[ct]; }
#pragma unroll
                for (int d = 1; d < 16; d <<= 1) rs += __shfl_xor(rs, d);
                li[rt][e] = li[rt][e] * alpha + rs;
#pragma unroll
                for (int dht = 0; dht < 4; ++dht) O[rt][dht][e] *= alpha;
                const int qlocal = rt * 16 + g * 4 + e;
#pragma unroll
                for (int ct = 0; ct < 8; ++ct) {
                    const int kchunk = ct * 2 + (r >> 3);
                    Pb[(kchunk * 32 + qlocal) * 8 + (r & 7)] = (bf16_t)pv[ct];
                }
            }
        }
#pragma unroll
        for (int kt = 0; kt < 4; ++kt) {
            const bf16x8 pf0 = lds[2048 + wave * 512 + (kt * 4 + g) * 32 + r];
            const bf16x8 pf1 = lds[2048 + wave * 512 + (kt * 4 + g) * 32 + 16 + r];
#pragma unroll
            for (int dht = 0; dht < 4; ++dht) {
                const bf16x8 vf = lds[1024 + (kt * 4 + g) * 64 + dht * 16 + r];
                O[0][dht] = __builtin_amdgcn_mfma_f32_16x16x32_bf16(pf0, vf, O[0][dht], 0, 0, 0);
                O[1][dht] = __builtin_amdgcn_mfma_f32_16x16x32_bf16(pf1, vf, O[1][dht], 0, 0, 0);
            }
        }
        __syncthreads();
    }

    const int b = bh >> 4, head = bh & 15;
#pragma unroll
    for (int rt = 0; rt < 2; ++rt) {
#pragma unroll
        for (int e = 0; e < 4; ++e) {
            const float inv = __builtin_amdgcn_rcpf(li[rt][e]);
            const int s = qw + rt * 16 + g * 4 + e;
            bf16_t* op = ctx + ((size_t)(b * SEQ + s)) * D_MODEL + head * DHEAD + r;
#pragma unroll
            for (int dht = 0; dht < 4; ++dht)
                op[dht * 16] = (bf16_t)(O[rt][dht][e] * inv);
        }
    }
}

// ---------------------------------------------------------------------------
extern "C" void kernel_launch(void* const* d_in, const int* in_sizes, int n_in,
                              void* d_out, int out_size, void* d_ws, size_t ws_size,
                              hipStream_t stream)
{
    (void)in_sizes; (void)n_in; (void)out_size; (void)ws_size;
    const float* x  = (const float*)d_in[0];
    const float* g1 = (const float*)d_in[2];
    const float* g2 = (const float*)d_in[3];
    const float* wq = (const float*)d_in[4];
    const float* wk = (const float*)d_in[5];
    const float* wv = (const float*)d_in[6];
    const float* wo = (const float*)d_in[7];
    const float* w1 = (const float*)d_in[8];
    const float* w2 = (const float*)d_in[9];
    const float* w3 = (const float*)d_in[10];
    float* out = (float*)d_out;
    char* ws = (char*)d_ws;
    const size_t MB = 1ull << 20;
    bf16_t* wqkvT = (bf16_t*)(ws + 0);        // 3072 x 1024
    bf16_t* woT   = (bf16_t*)(ws + 6  * MB);  // 1024 x 1024
    bf16_t* w13T  = (bf16_t*)(ws + 8  * MB);  // 8192 x 1024 (16-col-group ilv)
    bf16_t* w2T   = (bf16_t*)(ws + 24 * MB);  // 1024 x 4096
    bf16_t* hbuf  = (bf16_t*)(ws + 32 * MB);  // h / h2; reused as vT during attn
    bf16_t* qbuf  = (bf16_t*)(ws + 48 * MB);
    bf16_t* kbuf  = (bf16_t*)(ws + 64 * MB);
    bf16_t* vbuf  = (bf16_t*)(ws + 80 * MB);
    bf16_t* ctx   = (bf16_t*)(ws + 96 * MB);
    bf16_t* gate  = (bf16_t*)(ws + 48 * MB);  // 8192 x 4096, reuses q/k/v/ctx
    bf16_t* vTb   = hbuf;                     // [bh][dh][s], h dead post-QKV

    dim3 blk(256);
    transpose_cast_kernel<<<dim3(32, 32),  blk, 0, stream>>>(wq, wqkvT,             1024, 1024, 16, 0);
    transpose_cast_kernel<<<dim3(32, 32),  blk, 0, stream>>>(wk, wqkvT + 1024*1024, 1024, 1024, 16, 0);
    transpose_cast_kernel<<<dim3(32, 32),  blk, 0, stream>>>(wv, wqkvT + 2048*1024, 1024, 1024, 16, 0);
    transpose_cast_kernel<<<dim3(32, 32),  blk, 0, stream>>>(wo, woT,               1024, 1024, 16, 0);
    transpose_cast_kernel<<<dim3(128, 32), blk, 0, stream>>>(w1, w13T,              1024, 4096, 32, 0);
    transpose_cast_kernel<<<dim3(128, 32), blk, 0, stream>>>(w3, w13T,              1024, 4096, 32, 16);
    transpose_cast_kernel<<<dim3(32, 128), blk, 0, stream>>>(w2, w2T,               4096, 1024, 16, 0);

    rmsnorm_kernel<<<dim3(8192), blk, 0, stream>>>(x, g1, hbuf);

    gemm_kernel<0><<<dim3(24, 64), blk, 0, stream>>>(hbuf, wqkvT, 8192, 3072, 1024,
        qbuf, kbuf, vbuf, nullptr, nullptr, nullptr);

    transpose_v_kernel<<<dim3(32, 64), blk, 0, stream>>>(vbuf, vTb);

    attn_kernel<<<dim3(16, 64), blk, 0, stream>>>(qbuf, kbuf, vTb, ctx);

    gemm_kernel<1><<<dim3(8, 64), blk, 0, stream>>>(ctx, woT, 8192, 1024, 1024,
        nullptr, nullptr, nullptr, x, out, nullptr);

    rmsnorm_kernel<<<dim3(8192), blk, 0, stream>>>(out, g2, hbuf);

    gemm_kernel<2><<<dim3(64, 64), blk, 0, stream>>>(hbuf, w13T, 8192, 8192, 1024,
        nullptr, nullptr, nullptr, nullptr, nullptr, gate);

    gemm_kernel<3><<<dim3(8, 64), blk, 0, stream>>>(gate, w2T, 8192, 1024, 4096,
        nullptr, nullptr, nullptr, out, out, nullptr);
}